// Round 7
// baseline (789.148 us; speedup 1.0000x reference)
//
#include <hip/hip_runtime.h>
#include <cstdint>

#define BB 8
#define PP 4096
#define DD 256
#define CC 1024

#define TM 128
#define TN 128

#define XT_BYTES (33554432ull)   // 8*32 tiles * 128KB
#define WT_BYTES (1048576ull)    // 8 chunks * 128KB
#define TILE_BYTES 131072ull     // one (b,pt) or cy chunk: 128 rows x 256 k x 2 planes x 2B
#define STAGE_BYTES 8192ull      // one BK=16 stage within a tile

typedef _Float16 f16x8 __attribute__((ext_vector_type(8)));
typedef float f32x16 __attribute__((ext_vector_type(16)));
typedef unsigned long long u64;

__device__ __forceinline__ void async_load16(const void* src, void* lds_dst) {
    __builtin_amdgcn_global_load_lds(
        (const __attribute__((address_space(1))) uint32_t*)src,
        (__attribute__((address_space(3))) uint32_t*)lds_dst,
        16, 0, 0);
}

// ---------------------------------------------------------------------------
// init argmax cells (fallback path only): score 0.0 @ p=0
// ---------------------------------------------------------------------------
__global__ __launch_bounds__(256) void init_ws_kernel(u64* keys, int n) {
    int i = blockIdx.x * 256 + threadIdx.x;
    if (i < n) keys[i] = 0x00000000FFFFFFFFull;
}

// ---------------------------------------------------------------------------
// transform: fp32 [rows][256] -> fragment-ordered fp16 hi/lo planes.
// Output chunk (k16,rt,sp,slot) of 16B at ((k16*4+rt)*2+sp)*1024 + slot*16,
// slot = (row&31) + 32*ksub; k16 = k/16 in 0..15.
// Blocks 0..31 additionally init the 8192 argmax key cells (fused init).
// grid = 528: ids 0..511 -> x tile (id>>1), h=id&1; 512..527 -> W chunk.
// ---------------------------------------------------------------------------
__global__ __launch_bounds__(256) void transform_kernel(
    const float* __restrict__ x, const float* __restrict__ W,
    char* __restrict__ xT, char* __restrict__ wT, u64* __restrict__ keys)
{
    __shared__ float ls[64 * 260];   // 64 rows, stride 260 (pad: f4-aligned)

    const int id = blockIdx.x;
    const int t = threadIdx.x;
    if (id < 32) keys[id * 256 + t] = 0x00000000FFFFFFFFull;

    const int tile = id >> 1;
    const int h = id & 1;
    const float* src;
    char* dstTile;
    if (tile < 256) {
        src = x + (size_t)tile * 128 * 256;          // tile = b*32+pt
        dstTile = xT + (size_t)tile * TILE_BYTES;
    } else {
        int cy = tile - 256;
        src = W + (size_t)cy * 128 * 256;
        dstTile = wT + (size_t)cy * TILE_BYTES;
    }

    // load 64 rows x 256 k, coalesced
    #pragma unroll
    for (int i = 0; i < 16; ++i) {
        int c = i * 256 + t;              // 0..4095
        int row = c >> 6, kq = c & 63;
        float4 v = *reinterpret_cast<const float4*>(
            src + ((size_t)(h * 64 + row)) * 256 + kq * 4);
        *reinterpret_cast<float4*>(&ls[row * 260 + kq * 4]) = v;
    }
    __syncthreads();

    // emit 4096 16B chunks, coalesced (slot fastest)
    #pragma unroll
    for (int j = 0; j < 16; ++j) {
        int q = j * 256 + t;              // 0..4095
        int slot = q & 63;
        int sp = (q >> 6) & 1;
        int rtl = (q >> 7) & 1;
        int k16 = q >> 8;                 // 0..15
        int rowl = rtl * 32 + (slot & 31);
        int k = k16 * 16 + (slot >> 5) * 8;
        const float* p = &ls[rowl * 260 + k];
        f16x8 o;
        if (sp == 0) {
            #pragma unroll
            for (int i = 0; i < 8; ++i) o[i] = (_Float16)p[i];
        } else {
            #pragma unroll
            for (int i = 0; i < 8; ++i) {
                _Float16 hv = (_Float16)p[i];
                o[i] = (_Float16)((p[i] - (float)hv) * 4096.0f);
            }
        }
        int rt = h * 2 + rtl;
        size_t off = (((size_t)k16 * 4 + rt) * 2 + sp) * 1024 + (size_t)slot * 16;
        *reinterpret_cast<f16x8*>(dstTile + off) = o;
    }
}

// ---------------------------------------------------------------------------
// main GEMM: fp16-split MFMA (scores = relu(x @ W^T)) + per-column argmax.
// BK=16, 16 stages, LDS = 2 x 16KB -> up to 5 blocks/CU (occupancy lever).
// Counted-vmcnt pipeline: prologue issues stages 0,1; each stage waits
// vmcnt(4) (own 4 loads done, next stage's 4 in flight), s_barrier, compute
// (12 MFMA, 8 ds_read_b128), lgkmcnt(0)+s_barrier, issue stage st+2 into the
// freed buffer. vmcnt(0) only at the last stage. T5 setprio around MFMAs.
// NOTE round-6 bug fixed: stage stride is STAGE_BYTES (8192), not 16384.
// ---------------------------------------------------------------------------
__global__ __launch_bounds__(256, 4) void gemm_argmax_t_kernel(
    const char* __restrict__ xT, const char* __restrict__ wT,
    u64* __restrict__ keys)
{
    __shared__ __align__(16) char lds[2][16384];   // [buf][A 8KB | B 8KB]

    const int tid = threadIdx.x;
    const int lane = tid & 63;
    const int w = tid >> 6;
    const int wy = w >> 1, wx = w & 1;
    const int pt = blockIdx.x;
    const int cy = blockIdx.y;
    const int b  = blockIdx.z;
    const int p0 = pt * TM;
    const int c0 = cy * TN;

    const char* aTile = xT + ((size_t)(b * 32 + pt)) * TILE_BYTES;
    const char* bTile = wT + (size_t)cy * TILE_BYTES;

    // staging: waves 0,1 split A's 8KB/stage; waves 2,3 split B. 4x1KB each.
    const char* mySrc = (w < 2 ? aTile : bTile) + (size_t)(w & 1) * 4096 + (size_t)lane * 16;
    const int myDstOff = (w >= 2 ? 8192 : 0) + (w & 1) * 4096;

    f32x16 zero;
    #pragma unroll
    for (int i = 0; i < 16; ++i) zero[i] = 0.f;
    f32x16 acc_hi[2][2], acc_lo[2][2];
    #pragma unroll
    for (int i = 0; i < 2; ++i)
        #pragma unroll
        for (int j = 0; j < 2; ++j) { acc_hi[i][j] = zero; acc_lo[i][j] = zero; }

    // prologue: stage 0 into buf0, stage 1 into buf1 (8 loads in flight/wave)
    #pragma unroll
    for (int i = 0; i < 4; ++i)
        async_load16(mySrc + (size_t)i * 1024, &lds[0][myDstOff + i * 1024]);
    #pragma unroll
    for (int i = 0; i < 4; ++i)
        async_load16(mySrc + STAGE_BYTES + (size_t)i * 1024, &lds[1][myDstOff + i * 1024]);

    #pragma unroll
    for (int st = 0; st < 16; ++st) {
        const int buf = st & 1;
        // this stage's 4 loads done; next stage's 4 remain in flight
        if (st < 15) asm volatile("s_waitcnt vmcnt(4)" ::: "memory");
        else         asm volatile("s_waitcnt vmcnt(0)" ::: "memory");
        __builtin_amdgcn_s_barrier();

        const f16x8* A = (const f16x8*)&lds[buf][0];
        const f16x8* B = (const f16x8*)&lds[buf][8192];
        f16x8 xa[2][2], wb2[2][2];
        #pragma unroll
        for (int rt = 0; rt < 2; ++rt) {
            const int rg = wy * 2 + rt;
            xa[rt][0] = A[(rg * 2 + 0) * 64 + lane];
            xa[rt][1] = A[(rg * 2 + 1) * 64 + lane];
        }
        #pragma unroll
        for (int ct = 0; ct < 2; ++ct) {
            const int cg = wx * 2 + ct;
            wb2[ct][0] = B[(cg * 2 + 0) * 64 + lane];
            wb2[ct][1] = B[(cg * 2 + 1) * 64 + lane];
        }
        __builtin_amdgcn_s_setprio(1);
        #pragma unroll
        for (int rt = 0; rt < 2; ++rt)
            #pragma unroll
            for (int ct = 0; ct < 2; ++ct) {
                acc_hi[rt][ct] = __builtin_amdgcn_mfma_f32_32x32x16_f16(
                    xa[rt][0], wb2[ct][0], acc_hi[rt][ct], 0, 0, 0);
                acc_lo[rt][ct] = __builtin_amdgcn_mfma_f32_32x32x16_f16(
                    xa[rt][0], wb2[ct][1], acc_lo[rt][ct], 0, 0, 0);
                acc_lo[rt][ct] = __builtin_amdgcn_mfma_f32_32x32x16_f16(
                    xa[rt][1], wb2[ct][0], acc_lo[rt][ct], 0, 0, 0);
            }
        __builtin_amdgcn_s_setprio(0);

        // all LDS reads of buf complete across the block, then re-stage it
        asm volatile("s_waitcnt lgkmcnt(0)" ::: "memory");
        __builtin_amdgcn_s_barrier();
        if (st + 2 < 16) {
            const char* s = mySrc + (size_t)(st + 2) * STAGE_BYTES;
            #pragma unroll
            for (int i = 0; i < 4; ++i)
                async_load16(s + (size_t)i * 1024, &lds[buf][myDstOff + i * 1024]);
        }
    }

    // ---- epilogue: per-column argmax over this block's 128 rows ----
    u64* smax = reinterpret_cast<u64*>(&lds[0][0]);
    if (tid < TN) smax[tid] = 0ull;
    __syncthreads();

    #pragma unroll
    for (int ct = 0; ct < 2; ++ct) {
        u64 bk = 0ull;
        #pragma unroll
        for (int rt = 0; rt < 2; ++rt) {
            f32x16 h = acc_hi[rt][ct];
            f32x16 l = acc_lo[rt][ct];
            #pragma unroll
            for (int reg = 0; reg < 16; ++reg) {
                float v = fmaxf(h[reg] + l[reg] * (1.0f / 4096.0f), 0.f);
                int prow = p0 + (wy * 2 + rt) * 32 +
                           (reg & 3) + 8 * (reg >> 2) + 4 * (lane >> 5);
                u64 key = ((u64)__float_as_uint(v) << 32) |
                          (unsigned int)(0xFFFFFFFFu - (unsigned int)prow);
                bk = bk > key ? bk : key;
            }
        }
        u64 other = __shfl_xor(bk, 32, 64);
        bk = bk > other ? bk : other;
        if (lane < 32) {
            int col = (wx * 2 + ct) * 32 + (lane & 31);
            atomicMax(&smax[col], bk);
        }
    }
    __syncthreads();
    if (tid < TN) {
        atomicMax(&keys[(size_t)b * CC + c0 + tid], smax[tid]);
    }
}

// ---------------------------------------------------------------------------
// fallback (ws too small): in-kernel conversion version (round-2, verified)
// ---------------------------------------------------------------------------
__global__ __launch_bounds__(256, 2) void gemm_argmax_conv_kernel(
    const float* __restrict__ x, const float* __restrict__ W,
    u64* __restrict__ keys)
{
    __shared__ f16x8 lA[4][4][2][64];
    __shared__ f16x8 lB[4][4][2][64];

    const int tid = threadIdx.x;
    const int lane = tid & 63;
    const int w = tid >> 6;
    const int wy = w >> 1, wx = w & 1;
    const int p0 = blockIdx.x * TM;
    const int c0 = blockIdx.y * TN;
    const int b  = blockIdx.z;

    const float* xb = x + (size_t)b * PP * DD;

    f32x16 zero;
    #pragma unroll
    for (int i = 0; i < 16; ++i) zero[i] = 0.f;
    f32x16 acc_hi[2][2], acc_lo[2][2];
    #pragma unroll
    for (int i = 0; i < 2; ++i)
        #pragma unroll
        for (int j = 0; j < 2; ++j) { acc_hi[i][j] = zero; acc_lo[i][j] = zero; }

    for (int st = 0; st < 4; ++st) {
        const int k0 = st * 64;
        float4 gA[8], gB[8];
        #pragma unroll
        for (int v = 0; v < 4; ++v) {
            int pi = tid + 256 * v;
            int r  = pi >> 3;
            int ck = (pi & 7) * 8;
            const float* pa = xb + (size_t)(p0 + r) * DD + k0 + ck;
            gA[2 * v]     = *reinterpret_cast<const float4*>(pa);
            gA[2 * v + 1] = *reinterpret_cast<const float4*>(pa + 4);
            const float* pb = W + (size_t)(c0 + r) * DD + k0 + ck;
            gB[2 * v]     = *reinterpret_cast<const float4*>(pb);
            gB[2 * v + 1] = *reinterpret_cast<const float4*>(pb + 4);
        }
        __syncthreads();
        #pragma unroll
        for (int v = 0; v < 4; ++v) {
            int pi = tid + 256 * v;
            int r  = pi >> 3;
            int ph = pi & 7;
            int kk = ph >> 1;
            int half = ph & 1;
            int slot = (r & 31) + 32 * half;
            int rtp = r >> 5;
            float va[8] = {gA[2*v].x, gA[2*v].y, gA[2*v].z, gA[2*v].w,
                           gA[2*v+1].x, gA[2*v+1].y, gA[2*v+1].z, gA[2*v+1].w};
            f16x8 h1, h2;
            #pragma unroll
            for (int i = 0; i < 8; ++i) {
                _Float16 h = (_Float16)va[i];
                h1[i] = h;
                h2[i] = (_Float16)((va[i] - (float)h) * 4096.0f);
            }
            lA[kk][rtp][0][slot] = h1;
            lA[kk][rtp][1][slot] = h2;
            float vb[8] = {gB[2*v].x, gB[2*v].y, gB[2*v].z, gB[2*v].w,
                           gB[2*v+1].x, gB[2*v+1].y, gB[2*v+1].z, gB[2*v+1].w};
            f16x8 g1, g2;
            #pragma unroll
            for (int i = 0; i < 8; ++i) {
                _Float16 h = (_Float16)vb[i];
                g1[i] = h;
                g2[i] = (_Float16)((vb[i] - (float)h) * 4096.0f);
            }
            lB[kk][rtp][0][slot] = g1;
            lB[kk][rtp][1][slot] = g2;
        }
        __syncthreads();
        #pragma unroll
        for (int kk = 0; kk < 4; ++kk) {
            f16x8 xa[2][2], wb2[2][2];
            #pragma unroll
            for (int rt = 0; rt < 2; ++rt) {
                xa[rt][0] = lA[kk][wy * 2 + rt][0][lane];
                xa[rt][1] = lA[kk][wy * 2 + rt][1][lane];
            }
            #pragma unroll
            for (int ct = 0; ct < 2; ++ct) {
                wb2[ct][0] = lB[kk][wx * 2 + ct][0][lane];
                wb2[ct][1] = lB[kk][wx * 2 + ct][1][lane];
            }
            #pragma unroll
            for (int rt = 0; rt < 2; ++rt)
                #pragma unroll
                for (int ct = 0; ct < 2; ++ct) {
                    acc_hi[rt][ct] = __builtin_amdgcn_mfma_f32_32x32x16_f16(
                        xa[rt][0], wb2[ct][0], acc_hi[rt][ct], 0, 0, 0);
                    acc_lo[rt][ct] = __builtin_amdgcn_mfma_f32_32x32x16_f16(
                        xa[rt][0], wb2[ct][1], acc_lo[rt][ct], 0, 0, 0);
                    acc_lo[rt][ct] = __builtin_amdgcn_mfma_f32_32x32x16_f16(
                        xa[rt][1], wb2[ct][0], acc_lo[rt][ct], 0, 0, 0);
                }
        }
    }

    u64* smax = reinterpret_cast<u64*>(&lA[0][0][0][0]);
    __syncthreads();
    if (tid < TN) smax[tid] = 0ull;
    __syncthreads();

    #pragma unroll
    for (int ct = 0; ct < 2; ++ct) {
        u64 bk = 0ull;
        #pragma unroll
        for (int rt = 0; rt < 2; ++rt) {
            f32x16 h = acc_hi[rt][ct];
            f32x16 l = acc_lo[rt][ct];
            #pragma unroll
            for (int reg = 0; reg < 16; ++reg) {
                float v = fmaxf(h[reg] + l[reg] * (1.0f / 4096.0f), 0.f);
                int prow = p0 + (wy * 2 + rt) * 32 +
                           (reg & 3) + 8 * (reg >> 2) + 4 * (lane >> 5);
                u64 key = ((u64)__float_as_uint(v) << 32) |
                          (unsigned int)(0xFFFFFFFFu - (unsigned int)prow);
                bk = bk > key ? bk : key;
            }
        }
        u64 other = __shfl_xor(bk, 32, 64);
        bk = bk > other ? bk : other;
        if (lane < 32) {
            int col = (wx * 2 + ct) * 32 + (lane & 31);
            atomicMax(&smax[col], bk);
        }
    }
    __syncthreads();
    if (tid < TN) {
        atomicMax(&keys[(size_t)b * CC + c0 + tid], smax[tid]);
    }
}

// ---------------------------------------------------------------------------
// scatter: out[b, argmax_p(b,c), :] += W[c, :]
// ---------------------------------------------------------------------------
__global__ __launch_bounds__(64) void scatter_kernel(
    const u64* __restrict__ keys,
    const float* __restrict__ W,
    float* __restrict__ out)
{
    const int cell = blockIdx.x;
    const int c = cell & (CC - 1);
    const int b = cell >> 10;
    u64 key = keys[cell];
    unsigned int p = (0xFFFFFFFFu - (unsigned int)(key & 0xFFFFFFFFull)) & (PP - 1);

    const float* wrow = W + (size_t)c * DD;
    float* orow = out + ((size_t)b * PP + p) * DD;
    const int t = threadIdx.x;
    #pragma unroll
    for (int u = 0; u < 4; u++) {
        int idx = u * 64 + t;
        atomicAdd(&orow[idx], wrow[idx]);
    }
}

extern "C" void kernel_launch(void* const* d_in, const int* in_sizes, int n_in,
                              void* d_out, int out_size, void* d_ws, size_t ws_size,
                              hipStream_t stream) {
    const float* x = (const float*)d_in[0];   // [B, P, D] fp32
    const float* W = (const float*)d_in[1];   // [C, D]    fp32
    float* out = (float*)d_out;

    char* wsb = (char*)d_ws;
    u64* keys = (u64*)wsb;                          // 64 KB
    char* xT = wsb + 65536;
    char* wT = xT + XT_BYTES;
    const size_t need = 65536 + XT_BYTES + WT_BYTES;

    hipMemsetAsync(d_out, 0, (size_t)out_size * sizeof(float), stream);

    if (ws_size >= need) {
        transform_kernel<<<528, 256, 0, stream>>>(x, W, xT, wT, keys);
        dim3 grid(PP / TM, CC / TN, BB);
        gemm_argmax_t_kernel<<<grid, 256, 0, stream>>>(xT, wT, keys);
    } else {
        int n = BB * CC;
        init_ws_kernel<<<(n + 255) / 256, 256, 0, stream>>>(keys, n);
        dim3 grid(PP / TM, CC / TN, BB);
        gemm_argmax_conv_kernel<<<grid, 256, 0, stream>>>(x, W, keys);
    }

    {
        dim3 grid(BB * CC);
        scatter_kernel<<<grid, 64, 0, stream>>>(keys, W, out);
    }
}

// Round 8
// 85.172 us; speedup vs baseline: 9.2653x; 9.2653x over previous
//
#include <hip/hip_runtime.h>
#include <cstdint>

#define BB 8
#define PP 4096
#define DD 256
#define CC 1024

#define TM 128
#define TN 128

#define XT_BYTES (33554432ull)   // 8*32 tiles * 128KB
#define WT_BYTES (1048576ull)    // 8 chunks * 128KB
#define TILE_BYTES 131072ull     // one (b,pt) or cy chunk: 128 rows x 256 k x 2 planes x 2B
#define STAGE_BYTES 8192ull      // one BK=16 stage within a tile (one k16 block)

typedef _Float16 f16x8 __attribute__((ext_vector_type(8)));
typedef float f32x16 __attribute__((ext_vector_type(16)));
typedef unsigned long long u64;

__device__ __forceinline__ void async_load16(const void* src, void* lds_dst) {
    __builtin_amdgcn_global_load_lds(
        (const __attribute__((address_space(1))) uint32_t*)src,
        (__attribute__((address_space(3))) uint32_t*)lds_dst,
        16, 0, 0);
}

// ---------------------------------------------------------------------------
// init argmax cells (fallback path only): score 0.0 @ p=0
// ---------------------------------------------------------------------------
__global__ __launch_bounds__(256) void init_ws_kernel(u64* keys, int n) {
    int i = blockIdx.x * 256 + threadIdx.x;
    if (i < n) keys[i] = 0x00000000FFFFFFFFull;
}

// ---------------------------------------------------------------------------
// transform: fp32 [rows][256] -> fragment-ordered fp16 hi/lo planes.
// Output chunk (k16,rt,sp,slot) of 16B at ((k16*4+rt)*2+sp)*1024 + slot*16,
// slot = (row&31) + 32*ksub; k16 = k/16 in 0..15. One k16 block = 8KB = one
// BK=16 GEMM stage for that tile.
// Blocks 0..31 additionally init the 8192 argmax key cells (fused init).
// grid = 528: ids 0..511 -> x tile (id>>1), h=id&1; 512..527 -> W chunk.
// ---------------------------------------------------------------------------
__global__ __launch_bounds__(256) void transform_kernel(
    const float* __restrict__ x, const float* __restrict__ W,
    char* __restrict__ xT, char* __restrict__ wT, u64* __restrict__ keys)
{
    __shared__ float ls[64 * 260];   // 64 rows, stride 260 (pad: f4-aligned)

    const int id = blockIdx.x;
    const int t = threadIdx.x;
    if (id < 32) keys[id * 256 + t] = 0x00000000FFFFFFFFull;

    const int tile = id >> 1;
    const int h = id & 1;
    const float* src;
    char* dstTile;
    if (tile < 256) {
        src = x + (size_t)tile * 128 * 256;          // tile = b*32+pt
        dstTile = xT + (size_t)tile * TILE_BYTES;
    } else {
        int cy = tile - 256;
        src = W + (size_t)cy * 128 * 256;
        dstTile = wT + (size_t)cy * TILE_BYTES;
    }

    // load 64 rows x 256 k, coalesced
    #pragma unroll
    for (int i = 0; i < 16; ++i) {
        int c = i * 256 + t;              // 0..4095
        int row = c >> 6, kq = c & 63;
        float4 v = *reinterpret_cast<const float4*>(
            src + ((size_t)(h * 64 + row)) * 256 + kq * 4);
        *reinterpret_cast<float4*>(&ls[row * 260 + kq * 4]) = v;
    }
    __syncthreads();

    // emit 4096 16B chunks, coalesced (slot fastest)
    #pragma unroll
    for (int j = 0; j < 16; ++j) {
        int q = j * 256 + t;              // 0..4095
        int slot = q & 63;
        int sp = (q >> 6) & 1;
        int rtl = (q >> 7) & 1;
        int k16 = q >> 8;                 // 0..15
        int rowl = rtl * 32 + (slot & 31);
        int k = k16 * 16 + (slot >> 5) * 8;
        const float* p = &ls[rowl * 260 + k];
        f16x8 o;
        if (sp == 0) {
            #pragma unroll
            for (int i = 0; i < 8; ++i) o[i] = (_Float16)p[i];
        } else {
            #pragma unroll
            for (int i = 0; i < 8; ++i) {
                _Float16 hv = (_Float16)p[i];
                o[i] = (_Float16)((p[i] - (float)hv) * 4096.0f);
            }
        }
        int rt = h * 2 + rtl;
        size_t off = (((size_t)k16 * 4 + rt) * 2 + sp) * 1024 + (size_t)slot * 16;
        *reinterpret_cast<f16x8*>(dstTile + off) = o;
    }
}

// ---------------------------------------------------------------------------
// main GEMM: fp16-split MFMA (scores = relu(x @ W^T)) + per-column argmax.
// BK=16, 16 stages, 4-buffer LDS ring (64KB), depth-3 prefetch, ONE barrier
// per stage (buf-reuse distance 4 makes the trailing lgkm-fence+barrier
// unnecessary: at stage s's entry barrier all waves are past stage s-4's
// reads, and every ds_read is consumed by an MFMA before the wave reaches
// the next barrier). Counted vmcnt: at stage entry outstanding loads are
// {s,s+1,s+2} = 12; vmcnt(8) retires s's 4 (in-order completion). Tail:
// st=14 -> vmcnt(4), st=15 -> vmcnt(0). Staging issue is EARLY (right after
// the barrier) so HBM/L2 latency hides under ~3 stages of compute.
// launch_bounds(256,2): dual 128-reg accumulator forbids more (r7 lesson:
// (256,4) spilled acc to scratch -> 4GB/dispatch).
// ---------------------------------------------------------------------------
__global__ __launch_bounds__(256, 2) void gemm_argmax_t_kernel(
    const char* __restrict__ xT, const char* __restrict__ wT,
    u64* __restrict__ keys)
{
    __shared__ __align__(16) char lds[4][16384];   // ring: [buf][A 8KB | B 8KB]

    const int tid = threadIdx.x;
    const int lane = tid & 63;
    const int w = tid >> 6;
    const int wy = w >> 1, wx = w & 1;
    const int pt = blockIdx.x;
    const int cy = blockIdx.y;
    const int b  = blockIdx.z;
    const int p0 = pt * TM;
    const int c0 = cy * TN;

    const char* aTile = xT + ((size_t)(b * 32 + pt)) * TILE_BYTES;
    const char* bTile = wT + (size_t)cy * TILE_BYTES;

    // staging: waves 0,1 split A's 8KB/stage; waves 2,3 split B. 4x1KB each.
    const char* mySrc = (w < 2 ? aTile : bTile) + (size_t)(w & 1) * 4096 + (size_t)lane * 16;
    const int myDstOff = (w >= 2 ? 8192 : 0) + (w & 1) * 4096;

    f32x16 zero;
    #pragma unroll
    for (int i = 0; i < 16; ++i) zero[i] = 0.f;
    f32x16 acc_hi[2][2], acc_lo[2][2];
    #pragma unroll
    for (int i = 0; i < 2; ++i)
        #pragma unroll
        for (int j = 0; j < 2; ++j) { acc_hi[i][j] = zero; acc_lo[i][j] = zero; }

    // prologue: issue stages 0,1,2 into bufs 0,1,2 (12 loads in flight/wave)
    #pragma unroll
    for (int s = 0; s < 3; ++s)
        #pragma unroll
        for (int i = 0; i < 4; ++i)
            async_load16(mySrc + (size_t)s * STAGE_BYTES + (size_t)i * 1024,
                         &lds[s][myDstOff + i * 1024]);

    #pragma unroll
    for (int st = 0; st < 16; ++st) {
        const int buf = st & 3;
        // retire this stage's 4 loads; keep later stages' loads in flight
        if (st <= 13)      asm volatile("s_waitcnt vmcnt(8)" ::: "memory");
        else if (st == 14) asm volatile("s_waitcnt vmcnt(4)" ::: "memory");
        else               asm volatile("s_waitcnt vmcnt(0)" ::: "memory");
        __builtin_amdgcn_s_barrier();

        // early-issue staging for stage st+3 into buf[(st+3)&3] (last read
        // at stage st-1; all waves are past that)
        if (st + 3 < 16) {
            const char* s = mySrc + (size_t)(st + 3) * STAGE_BYTES;
            #pragma unroll
            for (int i = 0; i < 4; ++i)
                async_load16(s + (size_t)i * 1024,
                             &lds[(st + 3) & 3][myDstOff + i * 1024]);
        }

        const f16x8* A = (const f16x8*)&lds[buf][0];
        const f16x8* B = (const f16x8*)&lds[buf][8192];
        f16x8 xa[2][2], wb2[2][2];
        #pragma unroll
        for (int rt = 0; rt < 2; ++rt) {
            const int rg = wy * 2 + rt;
            xa[rt][0] = A[(rg * 2 + 0) * 64 + lane];
            xa[rt][1] = A[(rg * 2 + 1) * 64 + lane];
        }
        #pragma unroll
        for (int ct = 0; ct < 2; ++ct) {
            const int cg = wx * 2 + ct;
            wb2[ct][0] = B[(cg * 2 + 0) * 64 + lane];
            wb2[ct][1] = B[(cg * 2 + 1) * 64 + lane];
        }
        __builtin_amdgcn_s_setprio(1);
        #pragma unroll
        for (int rt = 0; rt < 2; ++rt)
            #pragma unroll
            for (int ct = 0; ct < 2; ++ct) {
                acc_hi[rt][ct] = __builtin_amdgcn_mfma_f32_32x32x16_f16(
                    xa[rt][0], wb2[ct][0], acc_hi[rt][ct], 0, 0, 0);
                acc_lo[rt][ct] = __builtin_amdgcn_mfma_f32_32x32x16_f16(
                    xa[rt][0], wb2[ct][1], acc_lo[rt][ct], 0, 0, 0);
                acc_lo[rt][ct] = __builtin_amdgcn_mfma_f32_32x32x16_f16(
                    xa[rt][1], wb2[ct][0], acc_lo[rt][ct], 0, 0, 0);
            }
        __builtin_amdgcn_s_setprio(0);
    }

    // ---- epilogue: per-column argmax over this block's 128 rows ----
    __syncthreads();   // all waves done with LDS ring before aliasing smax
    u64* smax = reinterpret_cast<u64*>(&lds[0][0]);
    if (tid < TN) smax[tid] = 0ull;
    __syncthreads();

    #pragma unroll
    for (int ct = 0; ct < 2; ++ct) {
        u64 bk = 0ull;
        #pragma unroll
        for (int rt = 0; rt < 2; ++rt) {
            f32x16 h = acc_hi[rt][ct];
            f32x16 l = acc_lo[rt][ct];
            #pragma unroll
            for (int reg = 0; reg < 16; ++reg) {
                float v = fmaxf(h[reg] + l[reg] * (1.0f / 4096.0f), 0.f);
                int prow = p0 + (wy * 2 + rt) * 32 +
                           (reg & 3) + 8 * (reg >> 2) + 4 * (lane >> 5);
                u64 key = ((u64)__float_as_uint(v) << 32) |
                          (unsigned int)(0xFFFFFFFFu - (unsigned int)prow);
                bk = bk > key ? bk : key;
            }
        }
        u64 other = __shfl_xor(bk, 32, 64);
        bk = bk > other ? bk : other;
        if (lane < 32) {
            int col = (wx * 2 + ct) * 32 + (lane & 31);
            atomicMax(&smax[col], bk);
        }
    }
    __syncthreads();
    if (tid < TN) {
        atomicMax(&keys[(size_t)b * CC + c0 + tid], smax[tid]);
    }
}

// ---------------------------------------------------------------------------
// fallback (ws too small): in-kernel conversion version (round-2, verified)
// ---------------------------------------------------------------------------
__global__ __launch_bounds__(256, 2) void gemm_argmax_conv_kernel(
    const float* __restrict__ x, const float* __restrict__ W,
    u64* __restrict__ keys)
{
    __shared__ f16x8 lA[4][4][2][64];
    __shared__ f16x8 lB[4][4][2][64];

    const int tid = threadIdx.x;
    const int lane = tid & 63;
    const int w = tid >> 6;
    const int wy = w >> 1, wx = w & 1;
    const int p0 = blockIdx.x * TM;
    const int c0 = blockIdx.y * TN;
    const int b  = blockIdx.z;

    const float* xb = x + (size_t)b * PP * DD;

    f32x16 zero;
    #pragma unroll
    for (int i = 0; i < 16; ++i) zero[i] = 0.f;
    f32x16 acc_hi[2][2], acc_lo[2][2];
    #pragma unroll
    for (int i = 0; i < 2; ++i)
        #pragma unroll
        for (int j = 0; j < 2; ++j) { acc_hi[i][j] = zero; acc_lo[i][j] = zero; }

    for (int st = 0; st < 4; ++st) {
        const int k0 = st * 64;
        float4 gA[8], gB[8];
        #pragma unroll
        for (int v = 0; v < 4; ++v) {
            int pi = tid + 256 * v;
            int r  = pi >> 3;
            int ck = (pi & 7) * 8;
            const float* pa = xb + (size_t)(p0 + r) * DD + k0 + ck;
            gA[2 * v]     = *reinterpret_cast<const float4*>(pa);
            gA[2 * v + 1] = *reinterpret_cast<const float4*>(pa + 4);
            const float* pb = W + (size_t)(c0 + r) * DD + k0 + ck;
            gB[2 * v]     = *reinterpret_cast<const float4*>(pb);
            gB[2 * v + 1] = *reinterpret_cast<const float4*>(pb + 4);
        }
        __syncthreads();
        #pragma unroll
        for (int v = 0; v < 4; ++v) {
            int pi = tid + 256 * v;
            int r  = pi >> 3;
            int ph = pi & 7;
            int kk = ph >> 1;
            int half = ph & 1;
            int slot = (r & 31) + 32 * half;
            int rtp = r >> 5;
            float va[8] = {gA[2*v].x, gA[2*v].y, gA[2*v].z, gA[2*v].w,
                           gA[2*v+1].x, gA[2*v+1].y, gA[2*v+1].z, gA[2*v+1].w};
            f16x8 h1, h2;
            #pragma unroll
            for (int i = 0; i < 8; ++i) {
                _Float16 h = (_Float16)va[i];
                h1[i] = h;
                h2[i] = (_Float16)((va[i] - (float)h) * 4096.0f);
            }
            lA[kk][rtp][0][slot] = h1;
            lA[kk][rtp][1][slot] = h2;
            float vb[8] = {gB[2*v].x, gB[2*v].y, gB[2*v].z, gB[2*v].w,
                           gB[2*v+1].x, gB[2*v+1].y, gB[2*v+1].z, gB[2*v+1].w};
            f16x8 g1, g2;
            #pragma unroll
            for (int i = 0; i < 8; ++i) {
                _Float16 h = (_Float16)vb[i];
                g1[i] = h;
                g2[i] = (_Float16)((vb[i] - (float)h) * 4096.0f);
            }
            lB[kk][rtp][0][slot] = g1;
            lB[kk][rtp][1][slot] = g2;
        }
        __syncthreads();
        #pragma unroll
        for (int kk = 0; kk < 4; ++kk) {
            f16x8 xa[2][2], wb2[2][2];
            #pragma unroll
            for (int rt = 0; rt < 2; ++rt) {
                xa[rt][0] = lA[kk][wy * 2 + rt][0][lane];
                xa[rt][1] = lA[kk][wy * 2 + rt][1][lane];
            }
            #pragma unroll
            for (int ct = 0; ct < 2; ++ct) {
                wb2[ct][0] = lB[kk][wx * 2 + ct][0][lane];
                wb2[ct][1] = lB[kk][wx * 2 + ct][1][lane];
            }
            #pragma unroll
            for (int rt = 0; rt < 2; ++rt)
                #pragma unroll
                for (int ct = 0; ct < 2; ++ct) {
                    acc_hi[rt][ct] = __builtin_amdgcn_mfma_f32_32x32x16_f16(
                        xa[rt][0], wb2[ct][0], acc_hi[rt][ct], 0, 0, 0);
                    acc_lo[rt][ct] = __builtin_amdgcn_mfma_f32_32x32x16_f16(
                        xa[rt][0], wb2[ct][1], acc_lo[rt][ct], 0, 0, 0);
                    acc_lo[rt][ct] = __builtin_amdgcn_mfma_f32_32x32x16_f16(
                        xa[rt][1], wb2[ct][0], acc_lo[rt][ct], 0, 0, 0);
                }
        }
    }

    u64* smax = reinterpret_cast<u64*>(&lA[0][0][0][0]);
    __syncthreads();
    if (tid < TN) smax[tid] = 0ull;
    __syncthreads();

    #pragma unroll
    for (int ct = 0; ct < 2; ++ct) {
        u64 bk = 0ull;
        #pragma unroll
        for (int rt = 0; rt < 2; ++rt) {
            f32x16 h = acc_hi[rt][ct];
            f32x16 l = acc_lo[rt][ct];
            #pragma unroll
            for (int reg = 0; reg < 16; ++reg) {
                float v = fmaxf(h[reg] + l[reg] * (1.0f / 4096.0f), 0.f);
                int prow = p0 + (wy * 2 + rt) * 32 +
                           (reg & 3) + 8 * (reg >> 2) + 4 * (lane >> 5);
                u64 key = ((u64)__float_as_uint(v) << 32) |
                          (unsigned int)(0xFFFFFFFFu - (unsigned int)prow);
                bk = bk > key ? bk : key;
            }
        }
        u64 other = __shfl_xor(bk, 32, 64);
        bk = bk > other ? bk : other;
        if (lane < 32) {
            int col = (wx * 2 + ct) * 32 + (lane & 31);
            atomicMax(&smax[col], bk);
        }
    }
    __syncthreads();
    if (tid < TN) {
        atomicMax(&keys[(size_t)b * CC + c0 + tid], smax[tid]);
    }
}

// ---------------------------------------------------------------------------
// scatter: out[b, argmax_p(b,c), :] += W[c, :]
// ---------------------------------------------------------------------------
__global__ __launch_bounds__(64) void scatter_kernel(
    const u64* __restrict__ keys,
    const float* __restrict__ W,
    float* __restrict__ out)
{
    const int cell = blockIdx.x;
    const int c = cell & (CC - 1);
    const int b = cell >> 10;
    u64 key = keys[cell];
    unsigned int p = (0xFFFFFFFFu - (unsigned int)(key & 0xFFFFFFFFull)) & (PP - 1);

    const float* wrow = W + (size_t)c * DD;
    float* orow = out + ((size_t)b * PP + p) * DD;
    const int t = threadIdx.x;
    #pragma unroll
    for (int u = 0; u < 4; u++) {
        int idx = u * 64 + t;
        atomicAdd(&orow[idx], wrow[idx]);
    }
}

extern "C" void kernel_launch(void* const* d_in, const int* in_sizes, int n_in,
                              void* d_out, int out_size, void* d_ws, size_t ws_size,
                              hipStream_t stream) {
    const float* x = (const float*)d_in[0];   // [B, P, D] fp32
    const float* W = (const float*)d_in[1];   // [C, D]    fp32
    float* out = (float*)d_out;

    char* wsb = (char*)d_ws;
    u64* keys = (u64*)wsb;                          // 64 KB
    char* xT = wsb + 65536;
    char* wT = xT + XT_BYTES;
    const size_t need = 65536 + XT_BYTES + WT_BYTES;

    hipMemsetAsync(d_out, 0, (size_t)out_size * sizeof(float), stream);

    if (ws_size >= need) {
        transform_kernel<<<528, 256, 0, stream>>>(x, W, xT, wT, keys);
        dim3 grid(PP / TM, CC / TN, BB);
        gemm_argmax_t_kernel<<<grid, 256, 0, stream>>>(xT, wT, keys);
    } else {
        int n = BB * CC;
        init_ws_kernel<<<(n + 255) / 256, 256, 0, stream>>>(keys, n);
        dim3 grid(PP / TM, CC / TN, BB);
        gemm_argmax_conv_kernel<<<grid, 256, 0, stream>>>(x, W, keys);
    }

    {
        dim3 grid(BB * CC);
        scatter_kernel<<<grid, 64, 0, stream>>>(keys, W, out);
    }
}